// Round 10
// baseline (99.027 us; speedup 1.0000x reference)
//
#include <hip/hip_runtime.h>
#include <hip/hip_bf16.h>

#define N_TOTAL 4096
#define C_DIM 256
#define K_NEG 128
#define HW 1024
#define TEMP_INV (1.0f / 0.07f)

typedef _Float16 h8 __attribute__((ext_vector_type(8)));
typedef _Float16 h2 __attribute__((ext_vector_type(2)));

// ---------------------------------------------------------------------------
// Kernel 1: normalize + transpose, single pass (unchanged from r9, passed).
// Also zeroes the completion counter used by nce's fused reduction.
// ---------------------------------------------------------------------------
__global__ __launch_bounds__(256) void norm_tr_kernel(
    const float* __restrict__ fq, const float* __restrict__ fk,
    _Float16* __restrict__ qh, _Float16* __restrict__ kh,
    unsigned* __restrict__ counter) {
  if (blockIdx.x == 0 && threadIdx.x == 0) *counter = 0u;

  const int bid = blockIdx.x;
  const int tensor = bid >> 8;         // 0=q, 1=k
  const int chunk = bid & 255;         // 16-row chunk
  const int n0 = chunk * 16;
  const int b = n0 / HW, s0 = n0 % HW;
  const float* base = (tensor ? fk : fq) + (size_t)b * C_DIM * HW + s0;
  _Float16* out = tensor ? kh : qh;
  const float scale_extra = tensor ? 1.0f : TEMP_INV;  // fold 1/T into q

  const int t = threadIdx.x;
  __shared__ float tile[16][C_DIM + 1];
  __shared__ float red[16][17];
  __shared__ float sinv[16];

  {
    const int c = t;
    const float* src = base + (size_t)c * HW;
#pragma unroll
    for (int p = 0; p < 4; ++p) {
      const float4 v = *(const float4*)(src + p * 4);
      tile[p * 4 + 0][c] = v.x;
      tile[p * 4 + 1][c] = v.y;
      tile[p * 4 + 2][c] = v.z;
      tile[p * 4 + 3][c] = v.w;
    }
  }
  __syncthreads();

  {
    const int s = t & 15, cg = t >> 4;
    float acc = 0.f;
#pragma unroll
    for (int i = 0; i < 16; ++i) {
      float v = tile[s][cg * 16 + i];
      acc = fmaf(v, v, acc);
    }
    red[s][cg] = acc;
  }
  __syncthreads();
  if (t < 16) {
    float tot = 0.f;
#pragma unroll
    for (int g = 0; g < 16; ++g) tot += red[t][g];
    sinv[t] = scale_extra / fmaxf(sqrtf(tot), 1e-12f);  // eps = 1e-12
  }
  __syncthreads();

  {
    const int s = t & 15, c16 = t >> 4;
    const float inv = sinv[s];
    h8 o0, o1;
#pragma unroll
    for (int j = 0; j < 8; ++j) o0[j] = (_Float16)(tile[s][c16 * 16 + j] * inv);
#pragma unroll
    for (int j = 0; j < 8; ++j)
      o1[j] = (_Float16)(tile[s][c16 * 16 + 8 + j] * inv);
    h8* dst = (h8*)(out + (size_t)(n0 + s) * C_DIM + c16 * 16);
    dst[0] = o0;
    dst[1] = o1;
  }
}

// ---------------------------------------------------------------------------
// Kernel 2: per-WAVE InfoNCE + fused mean. 1024 blocks x 4 independent
// waves; wave = one row. 8-lane unit processes 16 negatives sequentially;
// logits live in registers; LSE fully in-register (butterfly shfls).
// No LDS / no barriers in the hot path; block tail gone. Last finished
// block reduces loss_buf (threadfence + atomic counter idiom).
// ---------------------------------------------------------------------------
__global__ __launch_bounds__(256) void nce_kernel(
    const _Float16* __restrict__ qh, const _Float16* __restrict__ kh,
    const int* __restrict__ neg, float* __restrict__ loss_buf,
    unsigned* __restrict__ counter, float* __restrict__ out) {
  const int tid = threadIdx.x;
  const int w = tid >> 6, lane = tid & 63;
  const int sub = lane & 7;            // lane within 8-lane unit
  const int unit = lane >> 3;          // 0..7
  const int n = blockIdx.x * 4 + w;

  union H { h8 v; h2 p[4]; };

  // q row (1/T pre-folded) and positive k row: 8-way replicated, L2-hot
  const h8* qrow = (const h8*)(qh + (size_t)n * C_DIM);
  h8 qv[4];
#pragma unroll
  for (int i = 0; i < 4; ++i) qv[i] = qrow[i * 8 + sub];
  const h8* kpr = (const h8*)(kh + (size_t)n * C_DIM);
  h8 kp[4];
#pragma unroll
  for (int i = 0; i < 4; ++i) kp[i] = kpr[i * 8 + sub];

  const int* nrow = neg + (size_t)n * K_NEG;
  float x[16];

#pragma unroll
  for (int j = 0; j < 16; ++j) {
    int idx = nrow[j * 8 + unit];
    int r = idx + (idx >= n ? 1 : 0);  // self-exclusion shift
    const h8* kr = (const h8*)(kh + (size_t)r * C_DIM);
    float a0 = 0.f, a1 = 0.f;
#pragma unroll
    for (int i = 0; i < 4; ++i) {
      H a; a.v = qv[i];
      H b; b.v = kr[i * 8 + sub];      // unit covers 512B contiguous
      a0 = __builtin_amdgcn_fdot2(b.p[0], a.p[0], a0, false);
      a1 = __builtin_amdgcn_fdot2(b.p[1], a.p[1], a1, false);
      a0 = __builtin_amdgcn_fdot2(b.p[2], a.p[2], a0, false);
      a1 = __builtin_amdgcn_fdot2(b.p[3], a.p[3], a1, false);
    }
    float acc = a0 + a1;
    acc += __shfl_xor(acc, 1);
    acc += __shfl_xor(acc, 2);
    acc += __shfl_xor(acc, 4);
    x[j] = acc;                        // all 8 lanes of unit hold logit
  }

  // positive logit (every unit computes the same value)
  float lp;
  {
    float a0 = 0.f, a1 = 0.f;
#pragma unroll
    for (int i = 0; i < 4; ++i) {
      H a; a.v = qv[i];
      H b; b.v = kp[i];
      a0 = __builtin_amdgcn_fdot2(b.p[0], a.p[0], a0, false);
      a1 = __builtin_amdgcn_fdot2(b.p[1], a.p[1], a1, false);
      a0 = __builtin_amdgcn_fdot2(b.p[2], a.p[2], a0, false);
      a1 = __builtin_amdgcn_fdot2(b.p[3], a.p[3], a1, false);
    }
    float acc = a0 + a1;
    acc += __shfl_xor(acc, 1);
    acc += __shfl_xor(acc, 2);
    acc += __shfl_xor(acc, 4);
    lp = acc;
  }

  // in-register LSE over {16 local logits} x 8 units + lp
  float m = x[0];
#pragma unroll
  for (int j = 1; j < 16; ++j) m = fmaxf(m, x[j]);
  m = fmaxf(m, __shfl_xor(m, 8));
  m = fmaxf(m, __shfl_xor(m, 16));
  m = fmaxf(m, __shfl_xor(m, 32));
  const float M = fmaxf(m, lp);
  float s = 0.f;
#pragma unroll
  for (int j = 0; j < 16; ++j) s += __expf(x[j] - M);
  s += __shfl_xor(s, 8);
  s += __shfl_xor(s, 16);
  s += __shfl_xor(s, 32);
  const float total = s + __expf(lp - M);
  if (lane == 0) loss_buf[n] = M + __logf(total) - lp;

  // ---- fused mean: last block to finish reduces all 4096 losses ----
  __shared__ bool sdone;
  __syncthreads();
  if (tid == 0) {
    __threadfence();
    unsigned old = atomicAdd(counter, 1u);
    sdone = (old == gridDim.x - 1);
  }
  __syncthreads();
  if (sdone && w == 0) {
    __threadfence();
    float v = 0.f;
#pragma unroll
    for (int p = 0; p < 16; ++p) {
      const float4 f = ((const float4*)loss_buf)[p * 64 + lane];
      v += (f.x + f.y) + (f.z + f.w);
    }
#pragma unroll
    for (int off = 32; off; off >>= 1) v += __shfl_xor(v, off);
    if (lane == 0) out[0] = v * (1.0f / N_TOTAL);
  }
}

extern "C" void kernel_launch(void* const* d_in, const int* in_sizes, int n_in,
                              void* d_out, int out_size, void* d_ws,
                              size_t ws_size, hipStream_t stream) {
  const float* fq = (const float*)d_in[0];
  const float* fk = (const float*)d_in[1];
  const int* neg = (const int*)d_in[2];
  float* out = (float*)d_out;

  _Float16* qh = (_Float16*)d_ws;                            // 2 MiB
  _Float16* kh = qh + (size_t)N_TOTAL * C_DIM;               // 2 MiB
  float* loss_buf = (float*)(kh + (size_t)N_TOTAL * C_DIM);  // 16 KiB
  unsigned* counter = (unsigned*)(loss_buf + N_TOTAL);       // 4 B

  hipLaunchKernelGGL(norm_tr_kernel, dim3(512), dim3(256), 0, stream,
                     fq, fk, qh, kh, counter);
  hipLaunchKernelGGL(nce_kernel, dim3(N_TOTAL / 4), dim3(256), 0, stream,
                     qh, kh, neg, loss_buf, counter, out);
}

// Round 11
// 79.572 us; speedup vs baseline: 1.2445x; 1.2445x over previous
//
#include <hip/hip_runtime.h>
#include <hip/hip_bf16.h>

#define N_TOTAL 4096
#define C_DIM 256
#define K_NEG 128
#define HW 1024
#define TEMP_INV (1.0f / 0.07f)

typedef _Float16 h8 __attribute__((ext_vector_type(8)));
typedef float fv2 __attribute__((ext_vector_type(2)));

// ---------------------------------------------------------------------------
// Kernel 1: normalize + transpose, single pass. 512 blocks = 2 tensors x 256
// chunks of 16 full rows. q -> f16 rows with 1/T folded in; k -> fp8 e4m3
// rows (halves the gather traffic in nce; r10 analysis: gather is L2-
// random-throughput-bound, so bytes are the only lever).
// ---------------------------------------------------------------------------
__global__ __launch_bounds__(256) void norm_tr_kernel(
    const float* __restrict__ fq, const float* __restrict__ fk,
    _Float16* __restrict__ qh, unsigned char* __restrict__ kh8) {
  const int bid = blockIdx.x;
  const int tensor = bid >> 8;         // 0=q, 1=k
  const int chunk = bid & 255;         // 16-row chunk
  const int n0 = chunk * 16;
  const int b = n0 / HW, s0 = n0 % HW;
  const float* base = (tensor ? fk : fq) + (size_t)b * C_DIM * HW + s0;

  const int t = threadIdx.x;
  __shared__ float tile[16][C_DIM + 1];
  __shared__ float red[16][17];
  __shared__ float sinv[16];

  // ---- load: thread t = channel; 16 spatial floats as 4x float4 ----
  {
    const float* src = base + (size_t)t * HW;
#pragma unroll
    for (int p = 0; p < 4; ++p) {
      const float4 v = *(const float4*)(src + p * 4);
      tile[p * 4 + 0][t] = v.x;
      tile[p * 4 + 1][t] = v.y;
      tile[p * 4 + 2][t] = v.z;
      tile[p * 4 + 3][t] = v.w;
    }
  }
  __syncthreads();

  // ---- sum of squares per row ----
  {
    const int s = t & 15, cg = t >> 4;
    float acc = 0.f;
#pragma unroll
    for (int i = 0; i < 16; ++i) {
      float v = tile[s][cg * 16 + i];
      acc = fmaf(v, v, acc);
    }
    red[s][cg] = acc;
  }
  __syncthreads();
  if (t < 16) {
    float tot = 0.f;
#pragma unroll
    for (int g = 0; g < 16; ++g) tot += red[t][g];
    // q rows also carry 1/T so dots are logits directly
    const float scale_extra = tensor ? 1.0f : TEMP_INV;
    sinv[t] = scale_extra / fmaxf(sqrtf(tot), 1e-12f);  // eps = 1e-12
  }
  __syncthreads();

  if (tensor == 0) {
    // ---- q: write normalized f16; thread t -> row t&15, 16-ch chunk t>>4 --
    const int s = t & 15, c16 = t >> 4;
    const float inv = sinv[s];
    h8 o0, o1;
#pragma unroll
    for (int j = 0; j < 8; ++j) o0[j] = (_Float16)(tile[s][c16 * 16 + j] * inv);
#pragma unroll
    for (int j = 0; j < 8; ++j)
      o1[j] = (_Float16)(tile[s][c16 * 16 + 8 + j] * inv);
    h8* dst = (h8*)(qh + (size_t)(n0 + s) * C_DIM + c16 * 16);
    dst[0] = o0;
    dst[1] = o1;
  } else {
    // ---- k: write normalized fp8 e4m3; thread t -> row t>>4, 16B @ (t&15)
    const int s = t >> 4, c16 = t & 15;   // 16 lanes cover one 256B row
    const float inv = sinv[s];
    uint4 W;
#pragma unroll
    for (int p = 0; p < 4; ++p) {
      const int e = c16 * 16 + p * 4;
      unsigned u = 0;
      u = __builtin_amdgcn_cvt_pk_fp8_f32(tile[s][e + 0] * inv,
                                          tile[s][e + 1] * inv, u, false);
      u = __builtin_amdgcn_cvt_pk_fp8_f32(tile[s][e + 2] * inv,
                                          tile[s][e + 3] * inv, u, true);
      ((unsigned*)&W)[p] = u;
    }
    ((uint4*)(kh8 + (size_t)(n0 + s) * C_DIM))[c16] = W;
  }
}

// ---------------------------------------------------------------------------
// Kernel 2: per-row InfoNCE (r9 structure: block per row, 32 units of 8
// lanes, plain loss store). k rows gathered as fp8 (2 x 16B per lane per
// row = half the bytes of f16); decoded with HW cvt_pk_f32_fp8 + fmaf.
// ---------------------------------------------------------------------------
__global__ __launch_bounds__(256) void nce_kernel(
    const _Float16* __restrict__ qh, const unsigned char* __restrict__ kh8,
    const int* __restrict__ neg, float* __restrict__ loss_buf) {
  const int n = blockIdx.x;
  const int t = threadIdx.x;
  const int lane = t & 63;
  const int w = t >> 6;
  const int sub = lane & 7;              // lane within 8-lane dot unit
  const int unit = w * 8 + (lane >> 3);  // 0..31

  __shared__ float sneg[K_NEG];
  __shared__ float s_lpos;

  // ---- indices ----
  int r[4];
#pragma unroll
  for (int j = 0; j < 4; ++j) {
    int x = neg[(size_t)n * K_NEG + j * 32 + unit];
    r[j] = x + (x >= n ? 1 : 0);         // self-exclusion shift
  }
  // ---- q: lane sub owns elems [sub*16,+16) and [128+sub*16,+16) ----
  const h8* qrow = (const h8*)(qh + (size_t)n * C_DIM);
  h8 qv[4];
  qv[0] = qrow[2 * sub];
  qv[1] = qrow[2 * sub + 1];
  qv[2] = qrow[16 + 2 * sub];
  qv[3] = qrow[16 + 2 * sub + 1];
  float qf[32];
#pragma unroll
  for (int i = 0; i < 4; ++i)
#pragma unroll
    for (int e = 0; e < 8; ++e) qf[i * 8 + e] = (float)qv[i][e];

  // ---- positive row (unit 0): fp8, lane sub reads uint4 sub and 8+sub ----
  uint4 kp[2];
  if (unit == 0) {
    const uint4* kr = (const uint4*)(kh8 + (size_t)n * C_DIM);
    kp[0] = kr[sub];
    kp[1] = kr[8 + sub];
  }
  // ---- gathered k rows: 2 x uint4 per lane per row ----
  uint4 kd[4][2];
#pragma unroll
  for (int j = 0; j < 4; ++j) {
    const uint4* kr = (const uint4*)(kh8 + (size_t)r[j] * C_DIM);
    kd[j][0] = kr[sub];
    kd[j][1] = kr[8 + sub];
  }

  // fp8 uint4 (16 elems) dot against qf[base..base+16)
  auto dot16 = [&](const uint4& U, int base, float& acc) {
#pragma unroll
    for (int p = 0; p < 4; ++p) {
      const unsigned u = ((const unsigned*)&U)[p];
      fv2 ab = __builtin_amdgcn_cvt_pk_f32_fp8(u, false);
      fv2 cd = __builtin_amdgcn_cvt_pk_f32_fp8(u, true);
      acc = fmaf(ab.x, qf[base + p * 4 + 0], acc);
      acc = fmaf(ab.y, qf[base + p * 4 + 1], acc);
      acc = fmaf(cd.x, qf[base + p * 4 + 2], acc);
      acc = fmaf(cd.y, qf[base + p * 4 + 3], acc);
    }
  };

  // ---- 4 negative logits per unit ----
#pragma unroll
  for (int j = 0; j < 4; ++j) {
    float acc = 0.f;
    dot16(kd[j][0], 0, acc);
    dot16(kd[j][1], 16, acc);
    acc += __shfl_xor(acc, 1);
    acc += __shfl_xor(acc, 2);
    acc += __shfl_xor(acc, 4);
    if (sub == 0) sneg[j * 32 + unit] = acc;
  }
  // ---- positive logit ----
  if (unit == 0) {
    float acc = 0.f;
    dot16(kp[0], 0, acc);
    dot16(kp[1], 16, acc);
    acc += __shfl_xor(acc, 1);
    acc += __shfl_xor(acc, 2);
    acc += __shfl_xor(acc, 4);
    if (sub == 0) s_lpos = acc;
  }
  __syncthreads();

  // ---- wave 0: logsumexp over 129 logits (q carries 1/T) ----
  if (w == 0) {
    float lp = s_lpos;
    float x1 = sneg[lane];
    float x2 = sneg[lane + 64];
    float m = fmaxf(fmaxf(x1, x2), lp);
#pragma unroll
    for (int off = 32; off; off >>= 1) m = fmaxf(m, __shfl_xor(m, off));
    float s = __expf(x1 - m) + __expf(x2 - m);
#pragma unroll
    for (int off = 32; off; off >>= 1) s += __shfl_xor(s, off);
    if (lane == 0) loss_buf[n] = m + __logf(s) - lp;
  }
}

// ---------------------------------------------------------------------------
// Kernel 3: mean over 4096 per-row losses. One block, 1024 threads.
// (Separate kernel: r10 showed the atomic-counter fused tail costs ~15us.)
// ---------------------------------------------------------------------------
__global__ __launch_bounds__(1024) void reduce_kernel(
    const float* __restrict__ loss_buf, float* __restrict__ out) {
  const int t = threadIdx.x;
  const float4 v = ((const float4*)loss_buf)[t];
  float s = (v.x + v.y) + (v.z + v.w);
#pragma unroll
  for (int off = 32; off; off >>= 1) s += __shfl_xor(s, off);
  __shared__ float red[16];
  if ((t & 63) == 0) red[t >> 6] = s;
  __syncthreads();
  if (t < 16) {
    float x = red[t];
#pragma unroll
    for (int off = 8; off; off >>= 1) x += __shfl_xor(x, off);
    if (t == 0) out[0] = x * (1.0f / N_TOTAL);
  }
}

extern "C" void kernel_launch(void* const* d_in, const int* in_sizes, int n_in,
                              void* d_out, int out_size, void* d_ws,
                              size_t ws_size, hipStream_t stream) {
  const float* fq = (const float*)d_in[0];
  const float* fk = (const float*)d_in[1];
  const int* neg = (const int*)d_in[2];
  float* out = (float*)d_out;

  _Float16* qh = (_Float16*)d_ws;                              // 2 MiB
  unsigned char* kh8 = (unsigned char*)(qh + (size_t)N_TOTAL * C_DIM); // 1 MiB
  float* loss_buf = (float*)(kh8 + (size_t)N_TOTAL * C_DIM);   // 16 KiB

  hipLaunchKernelGGL(norm_tr_kernel, dim3(512), dim3(256), 0, stream,
                     fq, fk, qh, kh8);
  hipLaunchKernelGGL(nce_kernel, dim3(N_TOTAL), dim3(256), 0, stream,
                     qh, kh8, neg, loss_buf);
  hipLaunchKernelGGL(reduce_kernel, dim3(1), dim3(1024), 0, stream,
                     loss_buf, out);
}